// Round 9
// baseline (252.579 us; speedup 1.0000x reference)
//
#include <hip/hip_runtime.h>
#include <hip/hip_bf16.h>
#include <math.h>

#define SS 1024
#define DD 1024
#define AA 256
#define BB 16

typedef short short8 __attribute__((ext_vector_type(8)));
typedef float f32x4 __attribute__((ext_vector_type(4)));

typedef __attribute__((address_space(1))) const void gconst_t;
typedef __attribute__((address_space(3))) void lds_t;

static __device__ __forceinline__ short f2bf(float f) {
    __hip_bfloat16 h = __float2bfloat16(f);
    union { __hip_bfloat16 h; short s; } u; u.h = h;
    return u.s;
}

// ---------------------------------------------------------------------------
// Kernel 0: pack W1 (f32 [K=1024][N=256]) into bf16 MFMA-fragment order:
//   W1f[((kb*16 + fnb)*64 + l)*8 + j] = bf16( W1[kb*32 + (l>>4)*8 + j][fnb*16 + (l&15)] )
// A fragments use the same k-permutation, so any bijective k-order is valid.
// ---------------------------------------------------------------------------
__global__ __launch_bounds__(256) void w1cvt_kernel(
    const float* __restrict__ W1, short* __restrict__ W1f)
{
    const int g  = blockIdx.x * 256 + threadIdx.x;   // 0..32767
    const int l  = g & 63;
    const int nb = (g >> 6) & 15;
    const int kb = g >> 10;
    const int k0 = kb * 32 + ((l >> 4) << 3);
    const int n  = nb * 16 + (l & 15);
    short8 o;
    #pragma unroll
    for (int j = 0; j < 8; ++j) o[j] = f2bf(W1[(size_t)(k0 + j) * AA + n]);
    *reinterpret_cast<short8*>(&W1f[(size_t)g * 8]) = o;
}

// ---------------------------------------------------------------------------
// Kernel 1: scores = tanh(hidden @ W1 + b1) . v  via bf16 MFMA, 2-phase LDS
// pipeline (T3-minimum): BM=32, BN=256, BK=64. 512 blocks x 256 thr (4 waves).
// B double-buffered in LDS via global_load_lds (linear, fragment-ordered, so
// ds_read stride-16B is conflict-free). A prefetched to regs one step ahead.
// One vmcnt(0) + one raw s_barrier per K-step (stage of t+1 targets the
// buffer last read at t-1, whose reads completed before the t-1 barrier).
// ---------------------------------------------------------------------------
__global__ __launch_bounds__(256) void scores_mfma_kernel(
    const float* __restrict__ hidden, const short* __restrict__ W1f,
    const float* __restrict__ b1, const float* __restrict__ v,
    float* __restrict__ scores)
{
    __shared__ short Bl[2][16384];   // 2 x 32 KiB, fragment-ordered B K-slices
    __shared__ float red[4][32];

    const int tid  = threadIdx.x;
    const int w    = tid >> 6;
    const int l    = tid & 63;
    const int row0 = blockIdx.x * 32;

    // A: lane l reads rows row0+(l&15)(+16), cols ks*64 + kbl*32 + (l>>4)*8 + j
    const float* ha = hidden + (size_t)(row0 + (l & 15)) * DD + ((l >> 4) << 3);
    // B gll source (shorts): per-lane  w*512 + q*2048 + l*8  within the ks-slice
    const short* wsrc = W1f + w * 512 + l * 8;

    f32x4 acc[2][4];
    #pragma unroll
    for (int mi = 0; mi < 2; ++mi)
        #pragma unroll
        for (int nb = 0; nb < 4; ++nb)
            #pragma unroll
            for (int r = 0; r < 4; ++r) acc[mi][nb][r] = 0.f;

    float4 pf[2][2][2];   // [mi][kbl][half] — A prefetch registers (32 f32)

    // ---- prologue: stage B[0] into buf0, load A[0] ----
    #pragma unroll
    for (int q = 0; q < 8; ++q)
        __builtin_amdgcn_global_load_lds(
            (gconst_t*)(wsrc + (size_t)q * 2048),
            (lds_t*)(&Bl[0][w * 512 + q * 2048]), 16, 0, 0);
    #pragma unroll
    for (int mi = 0; mi < 2; ++mi)
        #pragma unroll
        for (int kbl = 0; kbl < 2; ++kbl)
            #pragma unroll
            for (int h = 0; h < 2; ++h)
                pf[mi][kbl][h] = *reinterpret_cast<const float4*>(
                    ha + (size_t)(mi * 16) * DD + kbl * 32 + h * 4);
    asm volatile("s_waitcnt vmcnt(0)" ::: "memory");
    __builtin_amdgcn_s_barrier();
    __builtin_amdgcn_sched_barrier(0);

    int cur = 0;
    for (int t = 0; t < 16; ++t) {
        // convert current A prefetch -> bf16 fragments (frees pf for t+1)
        short8 a[2][2];
        #pragma unroll
        for (int mi = 0; mi < 2; ++mi)
            #pragma unroll
            for (int kbl = 0; kbl < 2; ++kbl) {
                a[mi][kbl][0] = f2bf(pf[mi][kbl][0].x);
                a[mi][kbl][1] = f2bf(pf[mi][kbl][0].y);
                a[mi][kbl][2] = f2bf(pf[mi][kbl][0].z);
                a[mi][kbl][3] = f2bf(pf[mi][kbl][0].w);
                a[mi][kbl][4] = f2bf(pf[mi][kbl][1].x);
                a[mi][kbl][5] = f2bf(pf[mi][kbl][1].y);
                a[mi][kbl][6] = f2bf(pf[mi][kbl][1].z);
                a[mi][kbl][7] = f2bf(pf[mi][kbl][1].w);
            }

        if (t < 15) {
            // stage B[t+1] into the other buffer; prefetch A[t+1]
            const short* ws = wsrc + (size_t)(t + 1) * 16384;
            #pragma unroll
            for (int q = 0; q < 8; ++q)
                __builtin_amdgcn_global_load_lds(
                    (gconst_t*)(ws + (size_t)q * 2048),
                    (lds_t*)(&Bl[cur ^ 1][w * 512 + q * 2048]), 16, 0, 0);
            #pragma unroll
            for (int mi = 0; mi < 2; ++mi)
                #pragma unroll
                for (int kbl = 0; kbl < 2; ++kbl)
                    #pragma unroll
                    for (int h = 0; h < 2; ++h)
                        pf[mi][kbl][h] = *reinterpret_cast<const float4*>(
                            ha + (size_t)(mi * 16) * DD + (t + 1) * 64 + kbl * 32 + h * 4);
        }

        // compute on buf[cur]
        #pragma unroll
        for (int kbl = 0; kbl < 2; ++kbl)
            #pragma unroll
            for (int nb = 0; nb < 4; ++nb) {
                const short8 bf = *reinterpret_cast<const short8*>(
                    &Bl[cur][(kbl * 16 + w * 4 + nb) * 512 + l * 8]);
                acc[0][nb] = __builtin_amdgcn_mfma_f32_16x16x32_bf16(a[0][kbl], bf, acc[0][nb], 0, 0, 0);
                acc[1][nb] = __builtin_amdgcn_mfma_f32_16x16x32_bf16(a[1][kbl], bf, acc[1][nb], 0, 0, 0);
            }

        if (t < 15) {
            asm volatile("s_waitcnt vmcnt(0)" ::: "memory");
            __builtin_amdgcn_s_barrier();
            __builtin_amdgcn_sched_barrier(0);
        }
        cur ^= 1;
    }

    // epilogue: rowsum over this wave's 64 cols of tanh(x + b1) * v
    float b1l[4], vl[4];
    #pragma unroll
    for (int nb = 0; nb < 4; ++nb) {
        const int col = w * 64 + nb * 16 + (l & 15);
        b1l[nb] = b1[col];
        vl[nb]  = v[col];
    }
    #pragma unroll
    for (int mi = 0; mi < 2; ++mi) {
        #pragma unroll
        for (int r = 0; r < 4; ++r) {
            float s = tanhf(acc[mi][0][r] + b1l[0]) * vl[0]
                    + tanhf(acc[mi][1][r] + b1l[1]) * vl[1]
                    + tanhf(acc[mi][2][r] + b1l[2]) * vl[2]
                    + tanhf(acc[mi][3][r] + b1l[3]) * vl[3];
            s += __shfl_xor(s, 1, 64);
            s += __shfl_xor(s, 2, 64);
            s += __shfl_xor(s, 4, 64);
            s += __shfl_xor(s, 8, 64);
            if ((l & 15) == 0) red[w][mi * 16 + ((l >> 4) << 2) + r] = s;  // row = mi*16+(l>>4)*4+r
        }
    }
    __syncthreads();
    if (tid < 32)
        scores[row0 + tid] = red[0][tid] + red[1][tid] + red[2][tid] + red[3][tid];
}

// ---------------------------------------------------------------------------
// Kernel 2: fused softmax-prep + pooled-output scan.
// grid: B * (D/64) = 256 blocks, 1024 thr (16 waves). Wave owns 64 l's, lane one d.
// hv[64]: per-lane register cache of hidden[l,d] — hidden is read ONCE
// (statically unrolled indices so hv stays in VGPRs, rule #20).
// ---------------------------------------------------------------------------
__global__ __launch_bounds__(1024) void pool_kernel(
    const float* __restrict__ hidden, const float* __restrict__ scores,
    const int* __restrict__ pt, float* __restrict__ out)
{
    __shared__ float e_s[1024];
    __shared__ float iv_s[1024];
    __shared__ float seg[16][64];
    __shared__ float wmax[16];
    __shared__ float wsum[16];

    const int tid  = threadIdx.x;
    const int wave = tid >> 6;
    const int lane = tid & 63;
    const int b    = blockIdx.x >> 4;
    const int d    = (blockIdx.x & 15) * 64 + lane;

    // ---- prep: batch max ----
    const float s = scores[b * SS + tid];
    float mx = s;
    #pragma unroll
    for (int off = 32; off > 0; off >>= 1) mx = fmaxf(mx, __shfl_xor(mx, off, 64));
    if (lane == 0) wmax[wave] = mx;
    __syncthreads();
    float m = wmax[0];
    #pragma unroll
    for (int i = 1; i < 16; ++i) m = fmaxf(m, wmax[i]);

    // ---- prep: exp + inclusive prefix scan ----
    const float e = expf(s - m);
    float ps = e;
    #pragma unroll
    for (int off = 1; off < 64; off <<= 1) {
        const float t = __shfl_up(ps, off, 64);
        if (lane >= off) ps += t;
    }
    if (lane == 63) wsum[wave] = ps;
    __syncthreads();
    float pre = 0.f, Z = 0.f;
    #pragma unroll
    for (int i = 0; i < 16; ++i) {
        const float t = wsum[i];
        if (i < wave) pre += t;
        Z += t;
    }
    const float P = ps + pre;   // inclusive prefix sum of e up to tid

    const int type = pt[b];
    float iv;
    if (type == 0)        iv = 1.f / (P * (float)(tid + 1));
    else if (type == 1)   iv = 1.f / ((Z - P + e) * (float)(SS - tid));
    else                  iv = 1.f / ((Z - e) * (float)(SS - 1));
    e_s[tid]  = e;
    iv_s[tid] = iv;
    __syncthreads();

    // ---- load this wave's 64 hidden values once into registers ----
    const float* hb = hidden + (size_t)b * SS * DD + d;
    float*       ob = out    + (size_t)b * SS * DD + d;
    const int l0 = wave * 64;

    float hv[64];
    #pragma unroll
    for (int i = 0; i < 64; ++i) hv[i] = hb[(size_t)(l0 + i) * DD];

    float a0 = 0.f, a1 = 0.f, a2 = 0.f, a3 = 0.f;
    #pragma unroll
    for (int i = 0; i < 64; i += 4) {
        a0 += e_s[l0 + i + 0] * hv[i + 0];
        a1 += e_s[l0 + i + 1] * hv[i + 1];
        a2 += e_s[l0 + i + 2] * hv[i + 2];
        a3 += e_s[l0 + i + 3] * hv[i + 3];
    }
    seg[wave][lane] = (a0 + a1) + (a2 + a3);
    __syncthreads();

    // ---- per-type output pass (hidden from registers) ----
    if (type == 0) {                       // prefix: forward scan
        float run = 0.f;
        for (int w2 = 0; w2 < wave; ++w2) run += seg[w2][lane];
        #pragma unroll
        for (int i = 0; i < 64; ++i) {
            const int j = l0 + i;
            run += e_s[j] * hv[i];
            __builtin_nontemporal_store(run * iv_s[j], &ob[(size_t)j * DD]);
        }
    } else if (type == 1) {                // postfix: backward scan
        float run = 0.f;
        for (int w2 = wave + 1; w2 < 16; ++w2) run += seg[w2][lane];
        #pragma unroll
        for (int i = 63; i >= 0; --i) {
            const int j = l0 + i;
            run += e_s[j] * hv[i];
            __builtin_nontemporal_store(run * iv_s[j], &ob[(size_t)j * DD]);
        }
    } else {                               // cloze: total minus self
        float T = 0.f;
        #pragma unroll
        for (int w2 = 0; w2 < 16; ++w2) T += seg[w2][lane];
        #pragma unroll
        for (int i = 0; i < 64; ++i) {
            const int j = l0 + i;
            __builtin_nontemporal_store((T - e_s[j] * hv[i]) * iv_s[j],
                                        &ob[(size_t)j * DD]);
        }
    }
}

// ---------------------------------------------------------------------------
extern "C" void kernel_launch(void* const* d_in, const int* in_sizes, int n_in,
                              void* d_out, int out_size, void* d_ws, size_t ws_size,
                              hipStream_t stream) {
    const float* hidden = (const float*)d_in[0];
    const float* W1     = (const float*)d_in[1];
    const float* b1     = (const float*)d_in[2];
    const float* v      = (const float*)d_in[3];
    const int*   pt     = (const int*)  d_in[4];
    float* out = (float*)d_out;

    float* ws     = (float*)d_ws;
    float* scores = ws;                     // 16384 f32
    short* W1f    = (short*)(ws + BB * SS); // 262144 bf16 (512 KiB)

    w1cvt_kernel      <<<128, 256, 0, stream>>>(W1, W1f);
    scores_mfma_kernel<<<(BB * SS) / 32, 256, 0, stream>>>(hidden, W1f, b1, v, scores);
    pool_kernel       <<<BB * (DD / 64), 1024, 0, stream>>>(hidden, scores, pt, out);
}